// Round 4
// baseline (163.281 us; speedup 1.0000x reference)
//
#include <hip/hip_runtime.h>
#include <cmath>

// PRNNCell: B=64, I=512, H=1024, D=1536
//   x = concat(inputs, hidden)                       (B, D)
//   new_hidden = tanh(einsum('bd,bhd->bh', x, wih) + bih)
//   new_wih = wih + y*x*Wa + x*Wb + y*Wc + Wd        (y = new_hidden[b,h])
//   (dop in the reference is dead code -> skipped)
//
// R4 = R3 + 2-deep register software pipeline (prefetch next wih row during
// reduce/tanh/update of current row) + x kept in regs across both phases +
// fast tanh (1 - 2/(1+exp(2x)), saturates via inf). One block per h
// (1024 x 512 thr), Wa..d[h,:] in 24 KB LDS, wih streamed nontemporally once.

#define BB 64
#define II 512
#define HH 1024
#define DD 1536
#define NF4 (DD / 4)          // 384 vec4 per row
#define THREADS 512
#define PER_WAVE (BB / 8)     // 8 rows per wave

typedef float f4 __attribute__((ext_vector_type(4)));

__device__ __forceinline__ float fast_tanh(float x) {
    // exp overflow -> inf -> 2/inf = 0 -> y=1; underflow -> 0 -> y=-1. Correct.
    const float e = __expf(2.0f * x);
    return 1.0f - 2.0f / (1.0f + e);
}

__global__ __launch_bounds__(THREADS, 4) void prnn_fused(
    const float* __restrict__ inputs,   // B x I
    const float* __restrict__ hidden,   // B x H
    const float* __restrict__ wih,      // B x H x D
    const float* __restrict__ Wa,       // H x D
    const float* __restrict__ Wb,
    const float* __restrict__ Wc,
    const float* __restrict__ Wd,
    const float* __restrict__ bih,      // H
    float* __restrict__ out_h,          // B x H
    float* __restrict__ out_w)          // B x H x D
{
    __shared__ f4 sA[NF4], sB[NF4], sC[NF4], sD[NF4];   // 24 KB

    const int h    = blockIdx.x;
    const int tid  = threadIdx.x;
    const int lane = tid & 63;
    const int wid  = tid >> 6;

    if (tid < NF4) {
        sA[tid] = ((const f4*)(Wa + (size_t)h * DD))[tid];
        sB[tid] = ((const f4*)(Wb + (size_t)h * DD))[tid];
        sC[tid] = ((const f4*)(Wc + (size_t)h * DD))[tid];
        sD[tid] = ((const f4*)(Wd + (size_t)h * DD))[tid];
    }
    const float bh = bih[h];
    __syncthreads();

    const int b0 = wid * PER_WAVE;

    auto loadrow = [&](f4 (&wv)[6], int b) {
        const f4* __restrict__ wr = (const f4*)(wih + ((size_t)b * HH + h) * DD);
#pragma unroll
        for (int k = 0; k < 6; ++k)
            wv[k] = __builtin_nontemporal_load(&wr[lane + 64 * k]);
    };

    auto process = [&](f4 (&wv)[6], int b) {
        const f4* __restrict__ xin = (const f4*)(inputs + (size_t)b * II);
        const f4* __restrict__ xhi = (const f4*)(hidden + (size_t)b * HH);
        f4 xr[6];
        float dot = 0.f;
#pragma unroll
        for (int k = 0; k < 6; ++k) {
            const int j = lane + 64 * k;
            xr[k] = (k < 2) ? xin[j] : xhi[j - 128];
            dot += xr[k].x * wv[k].x + xr[k].y * wv[k].y
                 + xr[k].z * wv[k].z + xr[k].w * wv[k].w;
        }
#pragma unroll
        for (int off = 32; off >= 1; off >>= 1)
            dot += __shfl_xor(dot, off, 64);
        const float y = fast_tanh(dot + bh);
        const size_t r = (size_t)b * HH + h;
        if (lane == 0) out_h[r] = y;

        f4* __restrict__ orow = (f4*)(out_w + r * DD);
#pragma unroll
        for (int k = 0; k < 6; ++k) {
            const int j = lane + 64 * k;
            const f4 a  = sA[j];
            const f4 b2 = sB[j];
            const f4 c  = sC[j];
            const f4 d  = sD[j];
            f4 o;
            o.x = wv[k].x + xr[k].x * fmaf(y, a.x, b2.x) + fmaf(y, c.x, d.x);
            o.y = wv[k].y + xr[k].y * fmaf(y, a.y, b2.y) + fmaf(y, c.y, d.y);
            o.z = wv[k].z + xr[k].z * fmaf(y, a.z, b2.z) + fmaf(y, c.z, d.z);
            o.w = wv[k].w + xr[k].w * fmaf(y, a.w, b2.w) + fmaf(y, c.w, d.w);
            __builtin_nontemporal_store(o, &orow[j]);
        }
    };

    f4 wvA[6], wvB[6];
    loadrow(wvA, b0);                      // prologue
#pragma unroll
    for (int i = 0; i < PER_WAVE; i += 2) {
        loadrow(wvB, b0 + i + 1);          // prefetch overlaps process(A)
        process(wvA, b0 + i);
        if (i + 2 < PER_WAVE)
            loadrow(wvA, b0 + i + 2);      // prefetch overlaps process(B)
        process(wvB, b0 + i + 1);
    }
}

extern "C" void kernel_launch(void* const* d_in, const int* in_sizes, int n_in,
                              void* d_out, int out_size, void* d_ws, size_t ws_size,
                              hipStream_t stream) {
    const float* inputs = (const float*)d_in[0];
    const float* hidden = (const float*)d_in[1];
    const float* wih    = (const float*)d_in[2];
    const float* Wa     = (const float*)d_in[3];
    const float* Wb     = (const float*)d_in[4];
    const float* Wc     = (const float*)d_in[5];
    const float* Wd     = (const float*)d_in[6];
    const float* bih    = (const float*)d_in[7];
    // d_in[8] = W_dop, d_in[9] = b_dop: dead code in the reference, unused.

    float* out   = (float*)d_out;
    float* out_h = out;                    // B*H floats
    float* out_w = out + (size_t)BB * HH;  // B*H*D floats

    dim3 grid(HH), block(THREADS);
    prnn_fused<<<grid, block, 0, stream>>>(inputs, hidden, wih, Wa, Wb, Wc, Wd,
                                           bih, out_h, out_w);
}